// Round 9
// baseline (2691.009 us; speedup 1.0000x reference)
//
#include <hip/hip_runtime.h>
#include <math.h>

// Problem constants (4, 19, 512, 512) fp32
#define BB 4
#define CC 19
#define HH 512
#define WW 512
#define NSLICE (BB * CC)        // 76
#define SLICE  (HH * WW)        // 262144
#define W4     (WW / 4)         // 128 float4 per row
#define EPS    1e-12f
#define NEGINF (-INFINITY)

// time-tiling params
#define TSTEPS 16
#define NPASS  16               // 256 / TSTEPS

// Grid (R8, proven): 512 big tiles (64-out/96-in) + 192 small (32-out/64-in)
// = 704 blocks, big-first -> 2 full block-waves of bigs + 1 partial of smalls.
#define NBIG   512
#define NSMALL 192

// thread geometry (R9): 1024 threads = 16 waves x (R rows each) x 64 lanes
// x 8 cols.
//
// PROVEN FACTS DRIVING THIS CONFIG (R0-R8):
//  * Register budget: T threads -> ceil(T/64/4) waves/EU -> 512/that total
//    regs (half arch-VGPR half AGPR). 1024thr -> 128 total. c-only state
//    (48 floats/thread) fits CLEAN (R5: VGPR=64, WRITE=78MB pure).
//  * R5's x-streaming failed ONLY because blocks were round-robined across
//    XCDs -> per-XCD x working set ~15MB >> 4MiB L2 -> 815MB HBM fetch.
//    R7/R8's XCD-chunked swizzle pins ~9.5 slices per XCD -> x working set
//    ~2MB < L2, warm across all 16 passes. R9 = x-stream + chunked swizzle.
//  * 4 waves/SIMD (vs 2) doubles latency hiding on the max3/DPP chains
//    (R8 VALUBusy 46% = dependency-stalled half the time).
//  * DPP wave_shr/shl:1 halo exchange, old=-inf pad (R7: -23us/pass).
//  * ONE __syncthreads/step via double-buffered LDS halo snapshot (R7).
//  * Rolling hA/hB/hC body (each row consumed once -> short live ranges;
//    R6's deferred-commit variant spilled).
//  * Anti-LICM: asm("+v") on x offsets each step, else the compiler hoists
//    the t-invariant x loads into 48 persistent registers and spills (R5).
#define NW   16
#define COLS 8
#define THREADS 1024

struct F8 { float4 a, b; };

// DPP lane shifts (gfx9-family wave_shr:1 / wave_shl:1, valid on gfx950).
// bound_ctrl=false keeps `old` in the edge lane -> -inf image pad for free.
__device__ __forceinline__ float dpp_up(float src) {   // lane i <- lane i-1; lane0 -> -inf
    int o = __builtin_amdgcn_update_dpp(__float_as_int(NEGINF), __float_as_int(src),
                                        0x138 /*wave_shr:1*/, 0xF, 0xF, false);
    return __int_as_float(o);
}
__device__ __forceinline__ float dpp_dn(float src) {   // lane i <- lane i+1; lane63 -> -inf
    int o = __builtin_amdgcn_update_dpp(__float_as_int(NEGINF), __float_as_int(src),
                                        0x130 /*wave_shl:1*/, 0xF, 0xF, false);
    return __int_as_float(o);
}

// ---------------------------------------------------------------------------
__global__ void init_kernel(const float* __restrict__ x, float* __restrict__ cur) {
    int t = blockIdx.x * blockDim.x + threadIdx.x;
    const float4* x4 = (const float4*)x;
    float4* c4 = (float4*)cur;
    float4 v = x4[t];
    int pix = t << 2;
    int s = pix & (SLICE - 1);
    int i = s >> 9;
    int j0 = s & 511;
    float4 o;
    o.x = -v.x; o.y = -v.y; o.z = -v.z; o.w = -v.w;
    if (i == 0 || i == HH - 1) {
        o.x = 1.0f; o.y = 1.0f; o.z = 1.0f; o.w = 1.0f;
    } else {
        if (j0 == 0)        o.x = 1.0f;
        if (j0 == WW - 4)   o.w = 1.0f;
    }
    c4[t] = o;
}

// ---------------------------------------------------------------------------
// one tile = TSTEPS fused (maxpool3x3 * x) steps on a 512 x (NW*R) tile.
// R = rows/thread (compile-time), RR = valid output rows = NW*R - 32.
// c in registers; x streamed from (XCD-resident) L2 each step.
template<int R, int RR>
__device__ __forceinline__ void pass_body(const float* __restrict__ in,
                                          const float* __restrict__ xg,
                                          float* __restrict__ out,
                                          int bc, int tr0,
                                          float4 (&Tb)[2][NW][2][64],
                                          float4 (&Bb)[2][NW][2][64]) {
    const int tid  = threadIdx.x;
    const int lane = tid & 63;          // lane = column group (8 cols)
    const int w    = tid >> 6;          // wave = strip index 0..NW-1
    const int gstart = tr0 - TSTEPS;    // tile row a=0 -> global row
    const int row0   = gstart + w * R;  // this thread's r=0 global row
    const int col0   = lane * COLS;
    const size_t sbase = (size_t)bc * SLICE;
    const float* xb = xg + sbase;       // SGPR base; 32-bit per-thread offsets

    const float4 neg4 = make_float4(NEGINF, NEGINF, NEGINF, NEGINF);

    float4 cl[R], cr[R];
    int xoff[R];                        // row-clamped float offset of (row, col0)

#pragma unroll
    for (int r = 0; r < R; ++r) {
        int grow = row0 + r;
        int gcl  = min(max(grow, 0), HH - 1);       // clamp for x address
        xoff[r] = gcl * WW + col0;
        if (grow >= 0 && grow < HH) {               // wave-uniform branch
            const float4* p = (const float4*)(in + sbase + (size_t)grow * WW + col0);
            cl[r] = p[0]; cr[r] = p[1];
        } else { cl[r] = neg4; cr[r] = neg4; }
    }

    // horizontal 3-max of one 8-px row (a=cols0-3, b=cols4-7), DPP exchange
    auto hrow = [&](float4 a, float4 b) -> F8 {
        float lpx = dpp_up(b.w);       // left neighbor's col7; lane0 = -inf pad
        float rpx = dpp_dn(a.x);       // right neighbor's col0; lane63 = -inf pad
        F8 h;
        h.a.x = fmaxf(fmaxf(lpx, a.x), a.y);
        h.a.y = fmaxf(fmaxf(a.x, a.y), a.z);
        h.a.z = fmaxf(fmaxf(a.y, a.z), a.w);
        h.a.w = fmaxf(fmaxf(a.z, a.w), b.x);
        h.b.x = fmaxf(fmaxf(a.w, b.x), b.y);
        h.b.y = fmaxf(fmaxf(b.x, b.y), b.z);
        h.b.z = fmaxf(fmaxf(b.y, b.z), b.w);
        h.b.w = fmaxf(fmaxf(b.z, b.w), rpx);
        return h;
    };

    for (int t = 0; t < TSTEPS; ++t) {
        const int buf = t & 1;
        // break t-invariance of x addresses: without this, LICM hoists all
        // 2R x-float4 loads out of the t-loop -> 48 persistent regs -> spill
#pragma unroll
        for (int r = 0; r < R; ++r) asm volatile("" : "+v"(xoff[r]));

        // snapshot pre-step top/bottom rows for vertical neighbors
        Tb[buf][w][0][lane] = cl[0];
        Tb[buf][w][1][lane] = cr[0];
        Bb[buf][w][0][lane] = cl[R - 1];
        Bb[buf][w][1][lane] = cr[R - 1];
        __syncthreads();

        float4 upA, upB, dnA, dnB;
        if (w > 0) {                     // wave-uniform
            upA = Bb[buf][w - 1][0][lane];
            upB = Bb[buf][w - 1][1][lane];
        } else { upA = neg4; upB = neg4; }
        if (w < NW - 1) {
            dnA = Tb[buf][w + 1][0][lane];
            dnB = Tb[buf][w + 1][1][lane];
        } else { dnA = neg4; dnB = neg4; }

        F8 hA = hrow(upA, upB);          // row r-1 (neighbor)
        F8 hB = hrow(cl[0], cr[0]);      // row r
#pragma unroll
        for (int r = 0; r < R; ++r) {
            F8 hC;
            if (r + 1 < R) hC = hrow(cl[r + 1], cr[r + 1]);
            else           hC = hrow(dnA, dnB);
            // streamed x for this row (XCD-L2-resident)
            float4 xlv = *(const float4*)(xb + xoff[r]);
            float4 xrv = *(const float4*)(xb + xoff[r] + 4);
            float4 vl, vr;
            vl.x = fmaxf(fmaxf(hA.a.x, hB.a.x), hC.a.x);
            vl.y = fmaxf(fmaxf(hA.a.y, hB.a.y), hC.a.y);
            vl.z = fmaxf(fmaxf(hA.a.z, hB.a.z), hC.a.z);
            vl.w = fmaxf(fmaxf(hA.a.w, hB.a.w), hC.a.w);
            vr.x = fmaxf(fmaxf(hA.b.x, hB.b.x), hC.b.x);
            vr.y = fmaxf(fmaxf(hA.b.y, hB.b.y), hC.b.y);
            vr.z = fmaxf(fmaxf(hA.b.z, hB.b.z), hC.b.z);
            vr.w = fmaxf(fmaxf(hA.b.w, hB.b.w), hC.b.w);
            cl[r].x = vl.x * xlv.x;  cl[r].y = vl.y * xlv.y;
            cl[r].z = vl.z * xlv.z;  cl[r].w = vl.w * xlv.w;
            cr[r].x = vr.x * xrv.x;  cr[r].y = vr.y * xrv.y;
            cr[r].z = vr.z * xrv.z;  cr[r].w = vr.w * xrv.w;
            hA = hB; hB = hC;
        }
        // rows outside the image must be -inf before the next step's reads
#pragma unroll
        for (int r = 0; r < R; ++r) {
            int grow = row0 + r;
            if (grow < 0 || grow >= HH) { cl[r] = neg4; cr[r] = neg4; }  // uniform
        }
        // no trailing barrier: next step writes the OTHER buffer; this
        // buffer is rewritten only at step t+2, after barrier t+1.
    }

    // store valid center rows: tile rows a in [TSTEPS, TSTEPS+RR)
#pragma unroll
    for (int r = 0; r < R; ++r) {
        int a = w * R + r;               // wave-uniform condition
        if (a >= TSTEPS && a < TSTEPS + RR) {
            int grow = row0 + r;
            float4* p = (float4*)(out + sbase + (size_t)grow * WW + col0);
            p[0] = cl[r]; p[1] = cr[r];
        }
    }
}

// ---------------------------------------------------------------------------
__global__ __launch_bounds__(THREADS)
void pass_kernel(const float* __restrict__ in, const float* __restrict__ xg,
                 float* __restrict__ out) {
    // double-buffered top/bottom row snapshots; lane stride 16B ->
    // contiguous ds_read/write_b128, conflict-free (R5-measured). 128 KiB.
    __shared__ float4 Tb[2][NW][2][64];
    __shared__ float4 Bb[2][NW][2][64];

    const int bid = blockIdx.x;
    if (bid < NBIG) {
        // big tiles: 64-out/96-in. Bijective XCD swizzle over 512 = 8 x 64.
        const int g = (bid & 7) * (NBIG / 8) + (bid >> 3);
        int bc, tr0;
        if (g < 28 * 8) {                // slices 0..27: 8 big tiles each
            bc  = g >> 3;
            tr0 = (g & 7) << 6;
        } else {                         // slices 28..75: 6 big tiles each
            int g2 = g - 28 * 8;
            bc  = 28 + g2 / 6;
            tr0 = (g2 % 6) << 6;
        }
        pass_body<6, 64>(in, xg, out, bc, tr0, Tb, Bb);
    } else {
        // small tiles: 32-out/64-in, rows [384,512) of slices 28..75.
        // Bijective XCD swizzle over 192 = 8 x 24.
        const int sb = bid - NBIG;
        const int h  = (sb & 7) * (NSMALL / 8) + (sb >> 3);
        const int bc  = 28 + (h >> 2);
        const int tr0 = 384 + ((h & 3) << 5);
        pass_body<4, 32>(in, xg, out, bc, tr0, Tb, Bb);
    }
}

// ---------------------------------------------------------------------------
// final: norm over channel dim (19), out = cur * x / max(||cur||_2, eps)
__global__ void norm_kernel(const float* __restrict__ cur,
                            const float* __restrict__ x,
                            float* __restrict__ out) {
    int t = blockIdx.x * blockDim.x + threadIdx.x;
    int j4 = t & (W4 - 1);
    int i  = (t >> 7) & (HH - 1);
    int b  = t >> 16;
    size_t off = (size_t)b * CC * SLICE + (size_t)i * WW + (j4 << 2);

    float4 vals[CC];
    float sx = 0.f, sy = 0.f, sz = 0.f, sw = 0.f;
#pragma unroll
    for (int c = 0; c < CC; ++c) {
        float4 v = *(const float4*)(cur + off + (size_t)c * SLICE);
        vals[c] = v;
        sx += v.x * v.x; sy += v.y * v.y; sz += v.z * v.z; sw += v.w * v.w;
    }
    float4 r;
    r.x = 1.0f / fmaxf(sqrtf(sx), EPS);
    r.y = 1.0f / fmaxf(sqrtf(sy), EPS);
    r.z = 1.0f / fmaxf(sqrtf(sz), EPS);
    r.w = 1.0f / fmaxf(sqrtf(sw), EPS);
#pragma unroll
    for (int c = 0; c < CC; ++c) {
        float4 xv = *(const float4*)(x + off + (size_t)c * SLICE);
        float4 o;
        o.x = vals[c].x * xv.x * r.x;
        o.y = vals[c].y * xv.y * r.y;
        o.z = vals[c].z * xv.z * r.z;
        o.w = vals[c].w * xv.w * r.w;
        *(float4*)(out + off + (size_t)c * SLICE) = o;
    }
}

// ---------------------------------------------------------------------------
extern "C" void kernel_launch(void* const* d_in, const int* in_sizes, int n_in,
                              void* d_out, int out_size, void* d_ws, size_t ws_size,
                              hipStream_t stream) {
    const float* x = (const float*)d_in[0];
    float* out = (float*)d_out;
    float* ws  = (float*)d_ws;        // >= 79,691,776 B

    const int initBlocks = NSLICE * SLICE / 4 / 256; // 19456
    const int passBlocks = NBIG + NSMALL;            // 704
    const int normBlocks = BB * HH * W4 / 256;       // 1024

    init_kernel<<<initBlocks, 256, 0, stream>>>(x, ws);
    float* a = ws;
    float* b = out;
    for (int it = 0; it < NPASS; ++it) {
        pass_kernel<<<passBlocks, THREADS, 0, stream>>>(a, x, b);
        float* tmp = a; a = b; b = tmp;
    }
    // NPASS even -> result back in ws
    norm_kernel<<<normBlocks, 256, 0, stream>>>(ws, x, out);
}

// Round 10
// 2013.136 us; speedup vs baseline: 1.3367x; 1.3367x over previous
//
#include <hip/hip_runtime.h>
#include <math.h>

// Problem constants (4, 19, 512, 512) fp32
#define BB 4
#define CC 19
#define HH 512
#define WW 512
#define NSLICE (BB * CC)        // 76
#define SLICE  (HH * WW)        // 262144
#define W4     (WW / 4)         // 128 float4 per row
#define EPS    1e-12f
#define NEGINF (-INFINITY)

// time-tiling params
#define TSTEPS 16
#define NPASS  16               // 256 / TSTEPS

// Grid (R8, proven): 512 big tiles (64-out/96-in) + 192 small (32-out/64-in)
// = 704 blocks, big-first -> 2 full block-waves of bigs + 1 partial of smalls
// (R8: 135.5 -> 127.6us/pass; ~2% above the greedy-packing bound ~125us).
#define NBIG   512
#define NSMALL 192

// PROVEN FACTS (R0-R9):
//  * Register budget: T threads -> ceil(T/64/4) waves/EU -> 512/that total
//    regs (half arch-VGPR half AGPR). 512thr = 256 total; the 192-float c+x
//    state allocates CLEAN only with the rolling hA/hB/hC body. All
//    deviations spilled (R1-R4, R6: deferred-commit) or thrashed (R5/R9:
//    x-streaming -- 16x x re-reads = 1.9GB/pass demand vs 4MiB L2 shared
//    with the 200MB/pass c ping-pong -> 210MB/pass misses, net loss).
//  * Full persistence impossible: global c+x state 160MB > 128MB total RF.
//  * DPP wave_shr/shl:1 halo exchange, old=-inf pad (R7: -23us/pass vs
//    __shfl==ds_bpermute, whose DS latency is unhidden at 2 waves/SIMD).
//  * ONE __syncthreads/step via double-buffered LDS halo snapshot (R7).
//  * XCD-chunked bijective swizzle: slice row-blocks share an XCD's L2
//    (R7: FETCH 118 -> 105 MB).
//  * R10: init fused into pass 1 (c0 = border-masked(-x) derived from the
//    x bytes pass 1 loads anyway) -> init launch + 78MB ws write + 78MB
//    pass-1 c-read eliminated. Separate __global__ so steady-pass regalloc
//    is untouched (co-compiled template variants perturb codegen).
#define TX   64
#define TY   8
#define COLS 8
#define THREADS 512

struct F8 { float4 a, b; };

// DPP lane shifts (gfx9-family wave_shr:1 / wave_shl:1, valid on gfx950).
// bound_ctrl=false keeps `old` in the edge lane -> -inf image pad for free.
__device__ __forceinline__ float dpp_up(float src) {   // lane i <- lane i-1; lane0 -> -inf
    int o = __builtin_amdgcn_update_dpp(__float_as_int(NEGINF), __float_as_int(src),
                                        0x138 /*wave_shr:1*/, 0xF, 0xF, false);
    return __int_as_float(o);
}
__device__ __forceinline__ float dpp_dn(float src) {   // lane i <- lane i+1; lane63 -> -inf
    int o = __builtin_amdgcn_update_dpp(__float_as_int(NEGINF), __float_as_int(src),
                                        0x130 /*wave_shl:1*/, 0xF, 0xF, false);
    return __int_as_float(o);
}

// map blockIdx -> (slice, tile row0) with XCD-chunked bijective swizzle
__device__ __forceinline__ void tile_map(int bid, int& bc, int& tr0, bool& big) {
    if (bid < NBIG) {
        big = true;
        const int g = (bid & 7) * (NBIG / 8) + (bid >> 3);
        if (g < 28 * 8) {                // slices 0..27: 8 big tiles each
            bc  = g >> 3;
            tr0 = (g & 7) << 6;
        } else {                         // slices 28..75: 6 big tiles each
            int g2 = g - 28 * 8;
            bc  = 28 + g2 / 6;
            tr0 = (g2 % 6) << 6;
        }
    } else {
        big = false;                     // rows [384,512) of slices 28..75
        const int sb = bid - NBIG;
        const int h  = (sb & 7) * (NSMALL / 8) + (sb >> 3);
        bc  = 28 + (h >> 2);
        tr0 = 384 + ((h & 3) << 5);
    }
}

// ---------------------------------------------------------------------------
// one tile = TSTEPS fused (maxpool3x3 * x) steps on a 512 x (8R) tile.
// R = rows/thread (compile-time), RR = valid output rows = 8R - 32.
// FIRST: derive c0 = border-masked(-x) from the x load instead of reading
// the ping-pong buffer (init fusion).
template<int R, int RR, bool FIRST>
__device__ __forceinline__ void pass_body(const float* __restrict__ in,
                                          const float* __restrict__ xg,
                                          float* __restrict__ out,
                                          int bc, int tr0,
                                          float (&Tb)[2][TY][TX * 9],
                                          float (&Bb)[2][TY][TX * 9]) {
    const int tid  = threadIdx.x;
    const int tx   = tid & 63;          // lane = column group
    const int ty   = tid >> 6;          // wave = thread-row
    const int gstart = tr0 - TSTEPS;    // tile row a=0 -> global row
    const int row0   = gstart + ty * R; // this thread's r=0 global row
    const int col0   = tx * COLS;
    const size_t sbase = (size_t)bc * SLICE;

    const float4 neg4 = make_float4(NEGINF, NEGINF, NEGINF, NEGINF);
    const float4 one4 = make_float4(1.f, 1.f, 1.f, 1.f);

    float4 cl[R], cr[R], xl[R], xr_[R];

#pragma unroll
    for (int r = 0; r < R; ++r) {
        int grow = row0 + r;
        if (grow >= 0 && grow < HH) {               // wave-uniform branch
            const float4* q = (const float4*)(xg + sbase + (size_t)grow * WW + col0);
            xl[r] = q[0]; xr_[r] = q[1];
            if (FIRST) {
                // c0 = -x, with borders (row 0/511 all cols; col 0/511) = 1
                float4 ca, cb;
                ca.x = -xl[r].x;  ca.y = -xl[r].y;  ca.z = -xl[r].z;  ca.w = -xl[r].w;
                cb.x = -xr_[r].x; cb.y = -xr_[r].y; cb.z = -xr_[r].z; cb.w = -xr_[r].w;
                if (grow == 0 || grow == HH - 1) {  // wave-uniform
                    ca = one4; cb = one4;
                } else {
                    if (tx == 0)  ca.x = 1.0f;      // image left col
                    if (tx == 63) cb.w = 1.0f;      // image right col
                }
                cl[r] = ca; cr[r] = cb;
            } else {
                const float4* p = (const float4*)(in + sbase + (size_t)grow * WW + col0);
                cl[r] = p[0]; cr[r] = p[1];
            }
        } else {
            cl[r] = neg4; cr[r] = neg4; xl[r] = one4; xr_[r] = one4;
        }
    }

    // horizontal 3-max of one 8-px row (a=cols0-3, b=cols4-7), DPP exchange
    auto hrow = [&](float4 a, float4 b) -> F8 {
        float lpx = dpp_up(b.w);       // left neighbor's col7; lane0 = -inf pad
        float rpx = dpp_dn(a.x);       // right neighbor's col0; lane63 = -inf pad
        F8 h;
        h.a.x = fmaxf(fmaxf(lpx, a.x), a.y);
        h.a.y = fmaxf(fmaxf(a.x, a.y), a.z);
        h.a.z = fmaxf(fmaxf(a.y, a.z), a.w);
        h.a.w = fmaxf(fmaxf(a.z, a.w), b.x);
        h.b.x = fmaxf(fmaxf(a.w, b.x), b.y);
        h.b.y = fmaxf(fmaxf(b.x, b.y), b.z);
        h.b.z = fmaxf(fmaxf(b.y, b.z), b.w);
        h.b.w = fmaxf(fmaxf(b.z, b.w), rpx);
        return h;
    };

    for (int t = 0; t < TSTEPS; ++t) {
        const int buf = t & 1;
        float* tp = &Tb[buf][ty][tx * 9];
        float* bp = &Bb[buf][ty][tx * 9];
        // snapshot pre-step top/bottom rows for vertical neighbors
        tp[0] = cl[0].x;      tp[1] = cl[0].y;      tp[2] = cl[0].z;      tp[3] = cl[0].w;
        tp[4] = cr[0].x;      tp[5] = cr[0].y;      tp[6] = cr[0].z;      tp[7] = cr[0].w;
        bp[0] = cl[R - 1].x;  bp[1] = cl[R - 1].y;  bp[2] = cl[R - 1].z;  bp[3] = cl[R - 1].w;
        bp[4] = cr[R - 1].x;  bp[5] = cr[R - 1].y;  bp[6] = cr[R - 1].z;  bp[7] = cr[R - 1].w;
        __syncthreads();

        float4 upA, upB, dnA, dnB;
        if (ty > 0) {                    // wave-uniform
            const float* q = &Bb[buf][ty - 1][tx * 9];
            upA = make_float4(q[0], q[1], q[2], q[3]);
            upB = make_float4(q[4], q[5], q[6], q[7]);
        } else { upA = neg4; upB = neg4; }
        if (ty < TY - 1) {
            const float* q = &Tb[buf][ty + 1][tx * 9];
            dnA = make_float4(q[0], q[1], q[2], q[3]);
            dnB = make_float4(q[4], q[5], q[6], q[7]);
        } else { dnA = neg4; dnB = neg4; }

        F8 hA = hrow(upA, upB);          // row r-1 (neighbor)
        F8 hB = hrow(cl[0], cr[0]);      // row r
#pragma unroll
        for (int r = 0; r < R; ++r) {
            F8 hC;
            if (r + 1 < R) hC = hrow(cl[r + 1], cr[r + 1]);
            else           hC = hrow(dnA, dnB);
            float4 vl, vr;
            vl.x = fmaxf(fmaxf(hA.a.x, hB.a.x), hC.a.x);
            vl.y = fmaxf(fmaxf(hA.a.y, hB.a.y), hC.a.y);
            vl.z = fmaxf(fmaxf(hA.a.z, hB.a.z), hC.a.z);
            vl.w = fmaxf(fmaxf(hA.a.w, hB.a.w), hC.a.w);
            vr.x = fmaxf(fmaxf(hA.b.x, hB.b.x), hC.b.x);
            vr.y = fmaxf(fmaxf(hA.b.y, hB.b.y), hC.b.y);
            vr.z = fmaxf(fmaxf(hA.b.z, hB.b.z), hC.b.z);
            vr.w = fmaxf(fmaxf(hA.b.w, hB.b.w), hC.b.w);
            cl[r].x = vl.x * xl[r].x;  cl[r].y = vl.y * xl[r].y;
            cl[r].z = vl.z * xl[r].z;  cl[r].w = vl.w * xl[r].w;
            cr[r].x = vr.x * xr_[r].x; cr[r].y = vr.y * xr_[r].y;
            cr[r].z = vr.z * xr_[r].z; cr[r].w = vr.w * xr_[r].w;
            hA = hB; hB = hC;
        }
        // rows outside the image must be -inf before the next step's reads
#pragma unroll
        for (int r = 0; r < R; ++r) {
            int grow = row0 + r;
            if (grow < 0 || grow >= HH) { cl[r] = neg4; cr[r] = neg4; }  // uniform
        }
        // no trailing barrier: next step writes the OTHER buffer; this
        // buffer is rewritten only at step t+2, after barrier t+1.
    }

    // store valid center rows: tile rows a in [TSTEPS, TSTEPS+RR)
#pragma unroll
    for (int r = 0; r < R; ++r) {
        int a = ty * R + r;              // wave-uniform condition
        if (a >= TSTEPS && a < TSTEPS + RR) {
            int grow = row0 + r;
            float4* p = (float4*)(out + sbase + (size_t)grow * WW + col0);
            p[0] = cl[r]; p[1] = cr[r];
        }
    }
}

// ---------------------------------------------------------------------------
// steady pass (passes 2..16): reads ping-pong buffer. R8-identical codegen.
__global__ __launch_bounds__(THREADS, 1)
void pass_kernel(const float* __restrict__ in, const float* __restrict__ xg,
                 float* __restrict__ out) {
    __shared__ float Tb[2][TY][TX * 9];   // 9-word lane stride, dbuf; 72 KiB
    __shared__ float Bb[2][TY][TX * 9];
    int bc, tr0; bool big;
    tile_map(blockIdx.x, bc, tr0, big);
    if (big) pass_body<12, 64, false>(in, xg, out, bc, tr0, Tb, Bb);
    else     pass_body<8, 32, false>(in, xg, out, bc, tr0, Tb, Bb);
}

// first pass: c0 derived from x inline (init fusion). Separate __global__
// so the steady kernel's register allocation is untouched.
__global__ __launch_bounds__(THREADS, 1)
void pass_first_kernel(const float* __restrict__ xg, float* __restrict__ out) {
    __shared__ float Tb[2][TY][TX * 9];
    __shared__ float Bb[2][TY][TX * 9];
    int bc, tr0; bool big;
    tile_map(blockIdx.x, bc, tr0, big);
    if (big) pass_body<12, 64, true>(nullptr, xg, out, bc, tr0, Tb, Bb);
    else     pass_body<8, 32, true>(nullptr, xg, out, bc, tr0, Tb, Bb);
}

// ---------------------------------------------------------------------------
// final: norm over channel dim (19), out = cur * x / max(||cur||_2, eps)
__global__ void norm_kernel(const float* __restrict__ cur,
                            const float* __restrict__ x,
                            float* __restrict__ out) {
    int t = blockIdx.x * blockDim.x + threadIdx.x;
    int j4 = t & (W4 - 1);
    int i  = (t >> 7) & (HH - 1);
    int b  = t >> 16;
    size_t off = (size_t)b * CC * SLICE + (size_t)i * WW + (j4 << 2);

    float4 vals[CC];
    float sx = 0.f, sy = 0.f, sz = 0.f, sw = 0.f;
#pragma unroll
    for (int c = 0; c < CC; ++c) {
        float4 v = *(const float4*)(cur + off + (size_t)c * SLICE);
        vals[c] = v;
        sx += v.x * v.x; sy += v.y * v.y; sz += v.z * v.z; sw += v.w * v.w;
    }
    float4 r;
    r.x = 1.0f / fmaxf(sqrtf(sx), EPS);
    r.y = 1.0f / fmaxf(sqrtf(sy), EPS);
    r.z = 1.0f / fmaxf(sqrtf(sz), EPS);
    r.w = 1.0f / fmaxf(sqrtf(sw), EPS);
#pragma unroll
    for (int c = 0; c < CC; ++c) {
        float4 xv = *(const float4*)(x + off + (size_t)c * SLICE);
        float4 o;
        o.x = vals[c].x * xv.x * r.x;
        o.y = vals[c].y * xv.y * r.y;
        o.z = vals[c].z * xv.z * r.z;
        o.w = vals[c].w * xv.w * r.w;
        *(float4*)(out + off + (size_t)c * SLICE) = o;
    }
}

// ---------------------------------------------------------------------------
extern "C" void kernel_launch(void* const* d_in, const int* in_sizes, int n_in,
                              void* d_out, int out_size, void* d_ws, size_t ws_size,
                              hipStream_t stream) {
    const float* x = (const float*)d_in[0];
    float* out = (float*)d_out;
    float* ws  = (float*)d_ws;        // >= 79,691,776 B

    const int passBlocks = NBIG + NSMALL;            // 704
    const int normBlocks = BB * HH * W4 / 256;       // 1024

    // pass 1 (init fused): x -> out.  passes 2..16 ping-pong; with 16 total
    // passes the final result lands in ws (same parity as before).
    pass_first_kernel<<<passBlocks, THREADS, 0, stream>>>(x, out);
    float* a = out;
    float* b = ws;
    for (int it = 1; it < NPASS; ++it) {
        pass_kernel<<<passBlocks, THREADS, 0, stream>>>(a, x, b);
        float* tmp = a; a = b; b = tmp;
    }
    // result in ws
    norm_kernel<<<normBlocks, 256, 0, stream>>>(ws, x, out);
}